// Round 9
// baseline (168.174 us; speedup 1.0000x reference)
//
#include <hip/hip_runtime.h>
#include <stdint.h>

#define Nn 4
#define Cc 64
#define LL 4096   // H*W
#define KK 256    // feature dim: 64 channels * 4 causal taps
#define TRI2 528  // 32*33/2 triangular 128x128 tile pairs per batch

typedef _Float16 half8 __attribute__((ext_vector_type(8)));
typedef float f32x16 __attribute__((ext_vector_type(16)));
typedef float f32x4 __attribute__((ext_vector_type(4)));           // 16B aligned
typedef unsigned short ushort8v __attribute__((ext_vector_type(8)));

__device__ __forceinline__ unsigned f2ord(float f) {
    unsigned u = __float_as_uint(f);
    return u ^ ((u & 0x80000000u) ? 0xFFFFFFFFu : 0x80000000u);
}
__device__ __forceinline__ float ord2f(unsigned o) {
    unsigned u = (o & 0x80000000u) ? (o ^ 0x80000000u) : ~o;
    return __uint_as_float(u);
}
__device__ __forceinline__ unsigned short h2u(_Float16 h) {
    union { _Float16 f; unsigned short u; } x; x.f = h; return x.u;
}

// Ring-2 phase barrier: my previous-phase LDS reads drained (lgkm0) and my
// glds batch for the k16 about to be read has landed (vm0; issued one full
// phase earlier, so the wait is ~free). The s_barrier then makes ALL waves'
// staged chunks visible.
__device__ __forceinline__ void pipe_barrier() {
    asm volatile("s_waitcnt lgkmcnt(0) vmcnt(0)" ::: "memory");
    __builtin_amdgcn_s_barrier();
    __builtin_amdgcn_sched_barrier(0);
}

// Kernel 1: normalized masked context vectors, split fp16 hi/lo, both pre-scaled:
//   Vh' = 2048*fp16(v)  (exact pow2),  Vl = fp16((v - fp16(v)) * 2048)
// Both MFMA-FRAGMENT-PACKED:
//   addr(n,l,k) = (((n*128+(l>>5))*16+(k>>4))<<9) + ((k>>3)&1)*256 + (l&31)*8 + (k&7)
// ALSO emits yhatT[n][l][c] (channel-contiguous transpose) for writeout's gather.
// XCD-pinned and zeroes its slice of `best`.
__global__ __launch_bounds__(256) void build_v(const float* __restrict__ yhat,
                                               unsigned short* __restrict__ VhT,
                                               unsigned short* __restrict__ VlT,
                                               float* __restrict__ yhatT,
                                               unsigned long long* __restrict__ best) {
    int blk = blockIdx.x;                       // 0..1023
    int xcd = blk & 7;
    int n = xcd >> 1;
    int i64 = (blk >> 3) + (xcd & 1) * 128;     // 0..255; block covers l = i64*16 ..+16
    int tid = threadIdx.x;
    if (tid < 16) best[(size_t)n * LL + i64 * 16 + tid] = 0ull;

    int cg = tid & 15;           // channel group 0..15 (4 channels each) == k16 chunk
    int l = i64 * 16 + (tid >> 4);
    int y = l >> 6, x = l & 63;
    const float* src = yhat + (size_t)n * (Cc * LL);

    float vals[16];
    float ctr[4];
    float sumsq = 0.f;
#pragma unroll
    for (int ci = 0; ci < 4; ++ci) {
        const float* p = src + (cg * 4 + ci) * LL;
        float t0 = (y > 0 && x > 0)  ? p[l - 65] : 0.f;
        float t1 = (y > 0)           ? p[l - 64] : 0.f;
        float t2 = (y > 0 && x < 63) ? p[l - 63] : 0.f;
        float t3 = (x > 0)           ? p[l - 1]  : 0.f;
        ctr[ci] = p[l];
        vals[ci * 4 + 0] = t0; vals[ci * 4 + 1] = t1;
        vals[ci * 4 + 2] = t2; vals[ci * 4 + 3] = t3;
        sumsq += t0 * t0 + t1 * t1 + t2 * t2 + t3 * t3;
    }
    sumsq += __shfl_xor(sumsq, 1, 64);
    sumsq += __shfl_xor(sumsq, 2, 64);
    sumsq += __shfl_xor(sumsq, 4, 64);
    sumsq += __shfl_xor(sumsq, 8, 64);
    float inv = 1.f / fmaxf(sqrtf(sumsq), 1e-12f);

    // channel-contiguous transpose for writeout (16 threads x 16B = 256B/row)
    f32x4 cv; cv.x = ctr[0]; cv.y = ctr[1]; cv.z = ctr[2]; cv.w = ctr[3];
    *(f32x4*)(yhatT + ((size_t)n * LL + l) * 64 + cg * 4) = cv;

    // fragment-packed destination: 1KB chunk (rowblk,cg) + row slot
    size_t pk = ((((size_t)n * 128 + (l >> 5)) * 16 + cg) << 9) + (l & 31) * 8;
    unsigned short* dh = VhT + pk;
    unsigned short* dl = VlT + pk;
    ushort8v hA, hB, lA, lB;
#pragma unroll
    for (int kk = 0; kk < 16; ++kk) {           // kk = ci*4 + tp = k within chunk
        float v = vals[kk] * inv;
        _Float16 h = (fabsf(v) < 6.1035e-5f) ? (_Float16)0 : (_Float16)v;
        _Float16 lo = (_Float16)((v - (float)h) * 2048.0f);
        unsigned short hu = h2u(h * (_Float16)2048.0f);   // exact pow2 scale
        unsigned short lu = h2u(lo);
        if (kk < 8) { hA[kk] = hu; lA[kk] = lu; }
        else        { hB[kk - 8] = hu; lB[kk - 8] = lu; }
    }
    *(ushort8v*)(dh)       = hA;   // k8-half 0
    *(ushort8v*)(dh + 256) = hB;   // k8-half 1 (+256 halves = +512B)
    *(ushort8v*)(dl)       = lA;
    *(ushort8v*)(dl + 256) = lB;
}

// Kernel 2: triangular 128x128-tiled similarity-max via split-fp16 32x32x16 MFMA.
// acc = Al'Bh' + Ah'Bl + Ah'Bh' = 2^22 * v1.v2 ; val = acc * 2^-22.
// R9 = R8 minus the spills. R8 proved the occupancy lever (25->33%) but forcing
// <=128 combined regs spilled ~5 dwords/thread (WRITE_SIZE 4.2->15.5MB). Fix:
// shave TRUE demand below 128 by scalarizing glds addressing -- the old gsrc[4]
// held four 64-bit per-lane pointers (8 VGPR); every glds address is
// (wave-uniform chunk base) + lane*16B, so the base goes to SGPR (readfirstlane)
// and ONE shared lane-offset VGPR remains -> saddr-form global_load_lds.
// Everything else identical to R8: ring-2 (32KB), per-kc frag reads (phase A:
// kc0 frags + p1kc0; phase B: kc1 frags + 20 MFMA; carry ah0/bh0/bl0),
// per-acc-element MFMA order (p1k0,p1k1,p2k0,p2k1,p3k0,p3k1) UNCHANGED -> bit-exact.
// Supertile tile->block mapping (R7) kept.
__global__ __launch_bounds__(256, 4) void simmax(const unsigned short* __restrict__ Vh,
                                                 const unsigned short* __restrict__ Vl,
                                                 unsigned long long* __restrict__ best) {
    __shared__ __align__(16) unsigned short S[16384];   // 2 bufs x 16 chunks x 1KB = 32KB

    int bx = blockIdx.x;              // 0..2111
    int xcd = bx & 7, idx = bx >> 3;  // XCD-pin: each XCD owns half of one batch
    int n = xcd >> 1;
    int t = (xcd & 1) * 264 + idx;    // 0..527

    // supertile decode: column J, then off-diag/diag split
    int J = (int)((sqrtf(32.f * (float)t + 4.f) - 2.f) * 0.0625f);
    while (8 * (J + 1) * (J + 1) + 2 * (J + 1) <= t) ++J;
    while (8 * J * J + 2 * J > t) --J;
    int r = t - (8 * J * J + 2 * J);
    int i, j;
    if (r < 16 * J) {                 // off-diagonal supertile (I,J), I<J: 16 tiles
        int I = r >> 4, inner = r & 15;
        i = 4 * I + (inner & 3);
        j = 4 * J + (inner >> 2);
    } else {                          // diagonal supertile (J,J): 10 tiles, di<=dj
        int rr = r - 16 * J;
        int dj = (rr >= 6) ? 3 : (rr >= 3) ? 2 : (rr >= 1) ? 1 : 0;
        int di = rr - ((dj * (dj + 1)) >> 1);
        i = 4 * J + di;
        j = 4 * J + dj;
    }
    int l0 = i * 128, m0 = j * 128;

    int tid = threadIdx.x;
    int w = __builtin_amdgcn_readfirstlane(tid >> 6);   // wave id -> SGPR
    int lane = tid & 63;
    int r5 = lane & 31, h5 = lane >> 5;
    int rw = (w & 1) * 64;    // wave rows (l)
    int cw = (w >> 1) * 64;   // wave cols (m)
    bool skip = (i == j) && (rw == 64) && (cw == 0);  // fully l>m: no compute

    const unsigned short* VhB = Vh + (size_t)n * (LL * KK);
    const unsigned short* VlB = Vl + (size_t)n * (LL * KK);

    int aRow0 = l0 >> 5;              // block's first A rowblock (of 4)
    int bRow0 = m0 >> 5;              // block's first B rowblock (of 4)

    // staging: per k16 phase, wave w stages chunk idx = w*4+q (q=0..3).
    // Addressing split: SGPR chunk-base offset (readfirstlane) + shared
    // per-lane element offset -> compiler emits saddr-form global_load_lds.
    int laneElem = lane * 8;                    // per-lane offset (elements), 1 VGPR
    unsigned sOff[4];                           // scalar element offsets
    int lslot[4];                               // scalar LDS slots
#pragma unroll
    for (int q = 0; q < 4; ++q) {
        int cidx = w * 4 + q;                   // scalar
        int side = cidx >> 3, rb = (cidx >> 1) & 3;
        int rowblk = (side ? bRow0 : aRow0) + rb;
        sOff[q] = __builtin_amdgcn_readfirstlane(((unsigned)(rowblk * 16)) << 9);
        lslot[q] = cidx * 512;
    }

    int arb = (w & 1) * 2;            // wave A rowblock base (scalar)
    int brb = (w >> 1) * 2;           // wave B rowblock base (scalar)

    f32x16 acc[2][2];
#pragma unroll
    for (int r2 = 0; r2 < 2; ++r2)
#pragma unroll
        for (int c = 0; c < 2; ++c) acc[r2][c] = (f32x16)0.f;

    // chunk q parity selects hi/lo buffer: (w*4+q)&1
#define GLDS(KQ, BN)                                                              \
    do {                                                                          \
        _Pragma("unroll")                                                         \
        for (int q = 0; q < 4; ++q) {                                             \
            const unsigned short* sp =                                            \
                ((((w * 4 + q) & 1) ? VlB : VhB) + sOff[q] + (unsigned)(KQ) * 512); \
            __builtin_amdgcn_global_load_lds(                                     \
                (const __attribute__((address_space(1))) void*)(sp + laneElem),   \
                (__attribute__((address_space(3))) void*)(S + (BN) * 8192 + lslot[q]), 16, 0, 0); \
        }                                                                         \
    } while (0)

    // prologue: stage k16=0 -> buf0
    GLDS(0, 0);

#pragma unroll
    for (int kt = 0; kt < 8; ++kt) {
        // frags carried from phase A into phase B (ah0,bl0,bh0); al0 dies in A
        half8 ah0[2], bl0[2], bh0[2];

        // ---- phase A (k16 = 2kt, buf0): barrier, stage 2kt+1 -> buf1,
        //      read ALL kc0 frags, p1kc0 (4 MFMA)
        pipe_barrier();
        GLDS(2 * kt + 1, 1);
        if (!skip) {
            half8 al0[2];
#pragma unroll
            for (int r2 = 0; r2 < 2; ++r2) {
                al0[r2] = *(const half8*)(S + ((arb + r2) * 2 + 1) * 512 + laneElem);
                bh0[r2] = *(const half8*)(S + (8 + (brb + r2) * 2) * 512 + laneElem);
            }
#pragma unroll
            for (int r2 = 0; r2 < 2; ++r2) {
                ah0[r2] = *(const half8*)(S + ((arb + r2) * 2) * 512 + laneElem);
                bl0[r2] = *(const half8*)(S + (9 + (brb + r2) * 2) * 512 + laneElem);
            }
            __builtin_amdgcn_s_setprio(1);
#pragma unroll
            for (int r2 = 0; r2 < 2; ++r2)
#pragma unroll
                for (int c = 0; c < 2; ++c)
                    acc[r2][c] = __builtin_amdgcn_mfma_f32_32x32x16_f16(al0[r2], bh0[c], acc[r2][c], 0, 0, 0);
            __builtin_amdgcn_s_setprio(0);
        }

        // ---- phase B (k16 = 2kt+1, buf1): barrier, stage 2kt+2 -> buf0,
        //      read kc1 frags, remaining 20 MFMA
        pipe_barrier();
        if (kt < 7) GLDS(2 * kt + 2, 0);
        if (!skip) {
            half8 al1[2], ah1[2], bl1[2], bh1[2];
#pragma unroll
            for (int r2 = 0; r2 < 2; ++r2) {
                al1[r2] = *(const half8*)(S + 8192 + ((arb + r2) * 2 + 1) * 512 + laneElem);
                bh1[r2] = *(const half8*)(S + 8192 + (8 + (brb + r2) * 2) * 512 + laneElem);
            }
#pragma unroll
            for (int r2 = 0; r2 < 2; ++r2) {
                ah1[r2] = *(const half8*)(S + 8192 + ((arb + r2) * 2) * 512 + laneElem);
                bl1[r2] = *(const half8*)(S + 8192 + (9 + (brb + r2) * 2) * 512 + laneElem);
            }
            __builtin_amdgcn_s_setprio(1);
            // p1kc1
#pragma unroll
            for (int r2 = 0; r2 < 2; ++r2)
#pragma unroll
                for (int c = 0; c < 2; ++c)
                    acc[r2][c] = __builtin_amdgcn_mfma_f32_32x32x16_f16(al1[r2], bh1[c], acc[r2][c], 0, 0, 0);
            // p2kc0, p2kc1
#pragma unroll
            for (int r2 = 0; r2 < 2; ++r2)
#pragma unroll
                for (int c = 0; c < 2; ++c)
                    acc[r2][c] = __builtin_amdgcn_mfma_f32_32x32x16_f16(ah0[r2], bl0[c], acc[r2][c], 0, 0, 0);
#pragma unroll
            for (int r2 = 0; r2 < 2; ++r2)
#pragma unroll
                for (int c = 0; c < 2; ++c)
                    acc[r2][c] = __builtin_amdgcn_mfma_f32_32x32x16_f16(ah1[r2], bl1[c], acc[r2][c], 0, 0, 0);
            // p3kc0, p3kc1
#pragma unroll
            for (int r2 = 0; r2 < 2; ++r2)
#pragma unroll
                for (int c = 0; c < 2; ++c)
                    acc[r2][c] = __builtin_amdgcn_mfma_f32_32x32x16_f16(ah0[r2], bh0[c], acc[r2][c], 0, 0, 0);
#pragma unroll
            for (int r2 = 0; r2 < 2; ++r2)
#pragma unroll
                for (int c = 0; c < 2; ++c)
                    acc[r2][c] = __builtin_amdgcn_mfma_f32_32x32x16_f16(ah1[r2], bh1[c], acc[r2][c], 0, 0, 0);
            __builtin_amdgcn_s_setprio(0);
        }
    }
#undef GLDS

    if (skip) return;
    unsigned long long* bb = best + (size_t)n * LL;
    const float s = 1.f / 4194304.f;   // 2^-22
#pragma unroll
    for (int c = 0; c < 2; ++c) {
        int m = m0 + cw + c * 32 + r5;
        unsigned long long key = 0ull;
#pragma unroll
        for (int r2 = 0; r2 < 2; ++r2)
#pragma unroll
            for (int g = 0; g < 16; ++g) {
                int l = l0 + rw + r2 * 32 + (g & 3) + 8 * (g >> 2) + 4 * h5;
                if (l < m) {
                    float v = acc[r2][c][g] * s;
                    unsigned long long k2 =
                        ((unsigned long long)f2ord(v) << 32) |
                        (unsigned long long)(0xFFFFFFFFu - (unsigned)l);
                    key = (k2 > key) ? k2 : key;
                }
            }
        unsigned long long o = __shfl_xor(key, 32, 64);
        key = (o > key) ? o : key;
        if (h5 == 0 && key != 0ull) atomicMax(bb + m, key);
    }
}

// Kernel 3: unpack best, write S, U, ref_unfold, arg. Gather reads the
// channel-contiguous yhatT with lanes spanning c (coalesced 256B runs per m),
// transposes [patch][c] -> [f][m] through padded LDS, stores Rout coalesced.
// Block = (n, 16 m's). 1024 blocks, XCD-pinned.
__global__ __launch_bounds__(256) void writeout(const float* __restrict__ yhatT,
                                                const float* __restrict__ yprob,
                                                const unsigned long long* __restrict__ best,
                                                float* __restrict__ out) {
    __shared__ float P[576 * 17];             // [f][m] stride 17 (bank-spread), 39168B

    int blk = blockIdx.x;                     // 0..1023
    int xcd = blk & 7;
    int n = xcd >> 1;
    int mb = (blk >> 3) + (xcd & 1) * 128;    // 0..255
    int m0 = mb * 16;
    int tid = threadIdx.x;
    int ml = tid >> 4;                        // m_local 0..15
    int cs = (tid & 15) * 4;                  // channel start 0,4,..,60
    int m = m0 + ml;

    unsigned long long key = best[(size_t)n * LL + m];
    unsigned l = 0xFFFFFFFFu - (unsigned)(key & 0xFFFFFFFFull);
    float val = ord2f((unsigned)(key >> 32));
    bool zero = (m == 0);
    if (zero) l = 0;
    int ly = (int)(l >> 6), lx = (int)(l & 63);

    float* Sout = out;                       // [4,1,64,64]
    float* Uout = out + 16384;               // [4,1,64,64]
    float* Rout = out + 32768;               // [4,576,4096]
    float* Aout = out + 9469952;             // [4,4096] as float values

    if (cs == 0) {                            // one thread per m
        float S = zero ? 1e-8f : fminf(fmaxf(val, 1e-8f), 1.0f);
        float U = zero ? 1e-8f : fminf(fmaxf(yprob[(size_t)n * LL + l], 1e-8f), 1.0f);
        Sout[(size_t)n * LL + m] = S;
        Uout[(size_t)n * LL + m] = U;
        Aout[(size_t)n * LL + m] = zero ? -1.0f : (float)l;
    }

    // phase 1: gather 3x3 patch rows channel-contiguous, scatter into LDS [f][m]
    const float* T = yhatT + ((size_t)n * LL) * 64;
#pragma unroll
    for (int i = 0; i < 3; ++i) {
        int yy = ly + i - 1;
        bool rok = (!zero) && (yy >= 0) && (yy < 64);
#pragma unroll
        for (int jj = 0; jj < 3; ++jj) {
            int xx = lx + jj - 1;
            f32x4 v; v.x = 0.f; v.y = 0.f; v.z = 0.f; v.w = 0.f;
            if (rok && xx >= 0 && xx < 64)
                v = *(const f32x4*)(T + ((size_t)(yy * 64 + xx)) * 64 + cs);
            int ij = i * 3 + jj;
            P[((cs + 0) * 9 + ij) * 17 + ml] = v.x;
            P[((cs + 1) * 9 + ij) * 17 + ml] = v.y;
            P[((cs + 2) * 9 + ij) * 17 + ml] = v.z;
            P[((cs + 3) * 9 + ij) * 17 + ml] = v.w;
        }
    }
    __syncthreads();

    // phase 2: coalesced Rout stores (wave = 4 f x 16 m -> 4x64B segments)
    float* R = Rout + (size_t)n * (576 * LL) + m0;
    int fl = tid >> 4;                        // f offset within iteration
    int mm2 = tid & 15;
#pragma unroll 1
    for (int it2 = 0; it2 < 36; ++it2) {
        int f = it2 * 16 + fl;
        float v = P[f * 17 + mm2];
        __builtin_nontemporal_store(v, R + (size_t)f * LL + mm2);
    }
}

extern "C" void kernel_launch(void* const* d_in, const int* in_sizes, int n_in,
                              void* d_out, int out_size, void* d_ws, size_t ws_size,
                              hipStream_t stream) {
    const float* yhat  = (const float*)d_in[0];
    const float* yprob = (const float*)d_in[1];
    float* out = (float*)d_out;

    unsigned short* VhT = (unsigned short*)d_ws;                       // 8 MiB (fragment-packed)
    unsigned short* VlT = (unsigned short*)((char*)d_ws + 8388608);    // 8 MiB (fragment-packed)
    unsigned long long* best =
        (unsigned long long*)((char*)d_ws + 16777216);                 // 128 KiB
    float* yhatT = (float*)((char*)d_ws + 16908288);                   // 4 MiB transpose

    build_v<<<1024, 256, 0, stream>>>(yhat, VhT, VlT, yhatT, best);
    simmax<<<Nn * TRI2, 256, 0, stream>>>(VhT, VlT, best);
    writeout<<<1024, 256, 0, stream>>>(yhatT, yprob, best, out);
}

// Round 10
// 150.419 us; speedup vs baseline: 1.1180x; 1.1180x over previous
//
#include <hip/hip_runtime.h>
#include <stdint.h>

#define Nn 4
#define Cc 64
#define LL 4096   // H*W
#define KK 256    // feature dim: 64 channels * 4 causal taps
#define TRI2 528  // 32*33/2 triangular 128x128 tile pairs per batch

typedef _Float16 half8 __attribute__((ext_vector_type(8)));
typedef float f32x16 __attribute__((ext_vector_type(16)));
typedef float f32x4 __attribute__((ext_vector_type(4)));           // 16B aligned
typedef unsigned short ushort8v __attribute__((ext_vector_type(8)));

__device__ __forceinline__ unsigned f2ord(float f) {
    unsigned u = __float_as_uint(f);
    return u ^ ((u & 0x80000000u) ? 0xFFFFFFFFu : 0x80000000u);
}
__device__ __forceinline__ float ord2f(unsigned o) {
    unsigned u = (o & 0x80000000u) ? (o ^ 0x80000000u) : ~o;
    return __uint_as_float(u);
}
__device__ __forceinline__ unsigned short h2u(_Float16 h) {
    union { _Float16 f; unsigned short u; } x; x.f = h; return x.u;
}

// Counted-vmcnt raw barriers (T4). Batches are now 2 glds each: vmcnt(2)
// retires the batch issued two phases ago (the k16 about to be read) while
// the newest batch stays in flight. lgkmcnt(0) before s_barrier closes the
// LDS read-before-overwrite hazard.
__device__ __forceinline__ void pipe_barrier_vm2() {
    asm volatile("s_waitcnt lgkmcnt(0) vmcnt(2)" ::: "memory");
    __builtin_amdgcn_s_barrier();
    __builtin_amdgcn_sched_barrier(0);
}
__device__ __forceinline__ void pipe_barrier_vm0() {
    asm volatile("s_waitcnt lgkmcnt(0) vmcnt(0)" ::: "memory");
    __builtin_amdgcn_s_barrier();
    __builtin_amdgcn_sched_barrier(0);
}

// Kernel 1: normalized masked context vectors, split fp16 hi/lo, both pre-scaled:
//   Vh' = 2048*fp16(v)  (exact pow2),  Vl = fp16((v - fp16(v)) * 2048)
// Both MFMA-FRAGMENT-PACKED:
//   addr(n,l,k) = (((n*128+(l>>5))*16+(k>>4))<<9) + ((k>>3)&1)*256 + (l&31)*8 + (k&7)
// ALSO emits yhatT[n][l][c] (channel-contiguous transpose) for writeout's gather.
// XCD-pinned and zeroes its slice of `best`.
__global__ __launch_bounds__(256) void build_v(const float* __restrict__ yhat,
                                               unsigned short* __restrict__ VhT,
                                               unsigned short* __restrict__ VlT,
                                               float* __restrict__ yhatT,
                                               unsigned long long* __restrict__ best) {
    int blk = blockIdx.x;                       // 0..1023
    int xcd = blk & 7;
    int n = xcd >> 1;
    int i64 = (blk >> 3) + (xcd & 1) * 128;     // 0..255; block covers l = i64*16 ..+16
    int tid = threadIdx.x;
    if (tid < 16) best[(size_t)n * LL + i64 * 16 + tid] = 0ull;

    int cg = tid & 15;           // channel group 0..15 (4 channels each) == k16 chunk
    int l = i64 * 16 + (tid >> 4);
    int y = l >> 6, x = l & 63;
    const float* src = yhat + (size_t)n * (Cc * LL);

    float vals[16];
    float ctr[4];
    float sumsq = 0.f;
#pragma unroll
    for (int ci = 0; ci < 4; ++ci) {
        const float* p = src + (cg * 4 + ci) * LL;
        float t0 = (y > 0 && x > 0)  ? p[l - 65] : 0.f;
        float t1 = (y > 0)           ? p[l - 64] : 0.f;
        float t2 = (y > 0 && x < 63) ? p[l - 63] : 0.f;
        float t3 = (x > 0)           ? p[l - 1]  : 0.f;
        ctr[ci] = p[l];
        vals[ci * 4 + 0] = t0; vals[ci * 4 + 1] = t1;
        vals[ci * 4 + 2] = t2; vals[ci * 4 + 3] = t3;
        sumsq += t0 * t0 + t1 * t1 + t2 * t2 + t3 * t3;
    }
    sumsq += __shfl_xor(sumsq, 1, 64);
    sumsq += __shfl_xor(sumsq, 2, 64);
    sumsq += __shfl_xor(sumsq, 4, 64);
    sumsq += __shfl_xor(sumsq, 8, 64);
    float inv = 1.f / fmaxf(sqrtf(sumsq), 1e-12f);

    // channel-contiguous transpose for writeout (16 threads x 16B = 256B/row)
    f32x4 cv; cv.x = ctr[0]; cv.y = ctr[1]; cv.z = ctr[2]; cv.w = ctr[3];
    *(f32x4*)(yhatT + ((size_t)n * LL + l) * 64 + cg * 4) = cv;

    // fragment-packed destination: 1KB chunk (rowblk,cg) + row slot
    size_t pk = ((((size_t)n * 128 + (l >> 5)) * 16 + cg) << 9) + (l & 31) * 8;
    unsigned short* dh = VhT + pk;
    unsigned short* dl = VlT + pk;
    ushort8v hA, hB, lA, lB;
#pragma unroll
    for (int kk = 0; kk < 16; ++kk) {           // kk = ci*4 + tp = k within chunk
        float v = vals[kk] * inv;
        _Float16 h = (fabsf(v) < 6.1035e-5f) ? (_Float16)0 : (_Float16)v;
        _Float16 lo = (_Float16)((v - (float)h) * 2048.0f);
        unsigned short hu = h2u(h * (_Float16)2048.0f);   // exact pow2 scale
        unsigned short lu = h2u(lo);
        if (kk < 8) { hA[kk] = hu; lA[kk] = lu; }
        else        { hB[kk - 8] = hu; lB[kk - 8] = lu; }
    }
    *(ushort8v*)(dh)       = hA;   // k8-half 0
    *(ushort8v*)(dh + 256) = hB;   // k8-half 1 (+256 halves = +512B)
    *(ushort8v*)(dl)       = lA;
    *(ushort8v*)(dl + 256) = lB;
}

// Kernel 2: triangular 128x128-tiled similarity-max via split-fp16 32x32x16 MFMA.
// acc = Al'Bh' + Ah'Bl + Ah'Bh' = 2^22 * v1.v2 ; val = acc * 2^-22.
// R10: REGISTER-SHAPE FIX. R8/R9 proved the 4-wave 64x64-per-wave design has
// true demand ~144 combined regs (80 VGPR + 64 acc-AGPR) -> stuck at 8 waves/CU;
// forcing <=128 only spilled. New shape: 8 WAVES (512 thr), 64x32 per wave ->
// acc 32 AGPR, B-frags halve, staging 2 chunks/wave/phase. Estimated ~100
// combined -> 4 waves/SIMD NATURALLY (no launch-bounds forcing).
// Pipeline unchanged: ring-3 x 16KB LDS, 16 phases, counted vmcnt (now vm2),
// supertile map (R7). Fragment bytes + per-acc-element MFMA order
// (p1k0,p1k1,p2k0,p2k1,p3k0,p3k1) IDENTICAL -> bit-exact.
__global__ __launch_bounds__(512) void simmax(const unsigned short* __restrict__ Vh,
                                              const unsigned short* __restrict__ Vl,
                                              unsigned long long* __restrict__ best) {
    __shared__ __align__(16) unsigned short S[24576];   // 3 bufs x 16 chunks x 1KB = 48KB

    int bx = blockIdx.x;              // 0..2111
    int xcd = bx & 7, idx = bx >> 3;  // XCD-pin: each XCD owns half of one batch
    int n = xcd >> 1;
    int t = (xcd & 1) * 264 + idx;    // 0..527

    // supertile decode: column J, then off-diag/diag split
    int J = (int)((sqrtf(32.f * (float)t + 4.f) - 2.f) * 0.0625f);
    while (8 * (J + 1) * (J + 1) + 2 * (J + 1) <= t) ++J;
    while (8 * J * J + 2 * J > t) --J;
    int r = t - (8 * J * J + 2 * J);
    int i, j;
    if (r < 16 * J) {                 // off-diagonal supertile (I,J), I<J: 16 tiles
        int I = r >> 4, inner = r & 15;
        i = 4 * I + (inner & 3);
        j = 4 * J + (inner >> 2);
    } else {                          // diagonal supertile (J,J): 10 tiles, di<=dj
        int rr = r - 16 * J;
        int dj = (rr >= 6) ? 3 : (rr >= 3) ? 2 : (rr >= 1) ? 1 : 0;
        int di = rr - ((dj * (dj + 1)) >> 1);
        i = 4 * J + di;
        j = 4 * J + dj;
    }
    int l0 = i * 128, m0 = j * 128;

    int tid = threadIdx.x;
    int w = __builtin_amdgcn_readfirstlane(tid >> 6);   // wave id 0..7 -> SGPR
    int lane = tid & 63;
    int r5 = lane & 31, h5 = lane >> 5;
    int rw = (w & 1) * 64;    // wave rows (l): 0 or 64
    int cw = (w >> 1) * 32;   // wave cols (m): 0,32,64,96
    // diagonal tile: wave fully in l>m iff min_l >= max_m: rw=64, cw+32<=64
    bool skip = (i == j) && (rw == 64) && (cw < 64);

    const unsigned short* VhB = Vh + (size_t)n * (LL * KK);
    const unsigned short* VlB = Vl + (size_t)n * (LL * KK);

    int aRow0 = l0 >> 5;              // block's first A rowblock (of 4)
    int bRow0 = m0 >> 5;              // block's first B rowblock (of 4)

    // staging: per k16 phase, wave w stages chunks cidx = w*2+q (q=0..1).
    // cidx: side=cidx>>3 (A/B), rb=(cidx>>1)&3, lo=cidx&1. Same buffer layout
    // as R7: chunk idx in buffer = side*8 + rb*2 + lo, 1KB each.
    int laneElem = lane * 8;          // per-lane element offset
    const unsigned short* gsrc[2];
    int lslot[2];
#pragma unroll
    for (int q = 0; q < 2; ++q) {
        int cidx = w * 2 + q;                       // scalar
        int side = cidx >> 3, rb = (cidx >> 1) & 3, lo = cidx & 1;
        int rowblk = (side ? bRow0 : aRow0) + rb;
        gsrc[q] = (lo ? VlB : VhB) + ((size_t)(rowblk * 16) << 9) + laneElem;
        lslot[q] = cidx * 512;                      // scalar
    }

    int arb = (w & 1) * 2;            // wave A rowblock base (0 or 2), scalar
    int brb = (w >> 1);               // wave B rowblock (0..3), scalar

    f32x16 acc[2];                    // [r2] x single 32-col group = 32 AGPR
#pragma unroll
    for (int r2 = 0; r2 < 2; ++r2) acc[r2] = (f32x16)0.f;

#define GLDS(KQ, BN)                                                              \
    do {                                                                          \
        _Pragma("unroll")                                                         \
        for (int q = 0; q < 2; ++q)                                               \
            __builtin_amdgcn_global_load_lds(                                     \
                (const __attribute__((address_space(1))) void*)(gsrc[q] + (size_t)(KQ) * 512), \
                (__attribute__((address_space(3))) void*)(S + (BN) * 8192 + lslot[q]), 16, 0, 0); \
    } while (0)

    // prologue: stage k16=0 -> buf0, k16=1 -> buf1 (4 glds in flight)
    GLDS(0, 0);
    GLDS(1, 1);

#pragma unroll
    for (int kt = 0; kt < 8; ++kt) {
        const int b0 = (2 * kt) % 3;       // buffer holding kc0 (k16 = 2kt)
        const int b1 = (2 * kt + 1) % 3;   // buffer holding kc1

        // frags carried from phase A into phase B (ah0, bh0, bl0); al0 dies in A
        half8 ah0[2], bh0, bl0;

        // ---- phase A (k16 = 2kt, buf b0): barrier (k16=2kt landed; frees buf
        //      (2kt+2)%3), stage k16=2kt+2, read kc0 frags, p1kc0 (2 MFMA)
        pipe_barrier_vm2();
        if (kt < 7) GLDS(2 * kt + 2, (2 * kt + 2) % 3);
        if (!skip) {
            half8 al0[2];
#pragma unroll
            for (int r2 = 0; r2 < 2; ++r2) {
                al0[r2] = *(const half8*)(S + b0 * 8192 + ((arb + r2) * 2 + 1) * 512 + laneElem);
                ah0[r2] = *(const half8*)(S + b0 * 8192 + ((arb + r2) * 2) * 512 + laneElem);
            }
            bh0 = *(const half8*)(S + b0 * 8192 + (8 + brb * 2) * 512 + laneElem);
            bl0 = *(const half8*)(S + b0 * 8192 + (9 + brb * 2) * 512 + laneElem);
            __builtin_amdgcn_s_setprio(1);
#pragma unroll
            for (int r2 = 0; r2 < 2; ++r2)
                acc[r2] = __builtin_amdgcn_mfma_f32_32x32x16_f16(al0[r2], bh0, acc[r2], 0, 0, 0);
            __builtin_amdgcn_s_setprio(0);
        }

        // ---- phase B (k16 = 2kt+1, buf b1): barrier (k16=2kt+1 landed; frees
        //      buf b0 for k16=2kt+3), stage k16=2kt+3, read kc1 frags, 10 MFMA
        if (kt < 7) pipe_barrier_vm2();
        else        pipe_barrier_vm0();     // tail: drain
        if (kt < 7) GLDS(2 * kt + 3, (2 * kt + 3) % 3);

        if (!skip) {
            half8 al1[2], ah1[2], bh1, bl1;
#pragma unroll
            for (int r2 = 0; r2 < 2; ++r2) {
                al1[r2] = *(const half8*)(S + b1 * 8192 + ((arb + r2) * 2 + 1) * 512 + laneElem);
                ah1[r2] = *(const half8*)(S + b1 * 8192 + ((arb + r2) * 2) * 512 + laneElem);
            }
            bh1 = *(const half8*)(S + b1 * 8192 + (8 + brb * 2) * 512 + laneElem);
            bl1 = *(const half8*)(S + b1 * 8192 + (9 + brb * 2) * 512 + laneElem);
            __builtin_amdgcn_s_setprio(1);
            // per-acc-element order preserved: p1k1, p2k0, p2k1, p3k0, p3k1
#pragma unroll
            for (int r2 = 0; r2 < 2; ++r2)
                acc[r2] = __builtin_amdgcn_mfma_f32_32x32x16_f16(al1[r2], bh1, acc[r2], 0, 0, 0);
#pragma unroll
            for (int r2 = 0; r2 < 2; ++r2)
                acc[r2] = __builtin_amdgcn_mfma_f32_32x32x16_f16(ah0[r2], bl0, acc[r2], 0, 0, 0);
#pragma unroll
            for (int r2 = 0; r2 < 2; ++r2)
                acc[r2] = __builtin_amdgcn_mfma_f32_32x32x16_f16(ah1[r2], bl1, acc[r2], 0, 0, 0);
#pragma unroll
            for (int r2 = 0; r2 < 2; ++r2)
                acc[r2] = __builtin_amdgcn_mfma_f32_32x32x16_f16(ah0[r2], bh0, acc[r2], 0, 0, 0);
#pragma unroll
            for (int r2 = 0; r2 < 2; ++r2)
                acc[r2] = __builtin_amdgcn_mfma_f32_32x32x16_f16(ah1[r2], bh1, acc[r2], 0, 0, 0);
            __builtin_amdgcn_s_setprio(0);
        }
    }
#undef GLDS

    if (skip) return;
    unsigned long long* bb = best + (size_t)n * LL;
    const float s = 1.f / 4194304.f;   // 2^-22
    {
        int m = m0 + cw + r5;
        unsigned long long key = 0ull;
#pragma unroll
        for (int r2 = 0; r2 < 2; ++r2)
#pragma unroll
            for (int g = 0; g < 16; ++g) {
                int l = l0 + rw + r2 * 32 + (g & 3) + 8 * (g >> 2) + 4 * h5;
                if (l < m) {
                    float v = acc[r2][g] * s;
                    unsigned long long k2 =
                        ((unsigned long long)f2ord(v) << 32) |
                        (unsigned long long)(0xFFFFFFFFu - (unsigned)l);
                    key = (k2 > key) ? k2 : key;
                }
            }
        unsigned long long o = __shfl_xor(key, 32, 64);
        key = (o > key) ? o : key;
        if (h5 == 0 && key != 0ull) atomicMax(bb + m, key);
    }
}

// Kernel 3: unpack best, write S, U, ref_unfold, arg. Gather reads the
// channel-contiguous yhatT with lanes spanning c (coalesced 256B runs per m),
// transposes [patch][c] -> [f][m] through padded LDS, stores Rout coalesced.
// Block = (n, 16 m's). 1024 blocks, XCD-pinned.
__global__ __launch_bounds__(256) void writeout(const float* __restrict__ yhatT,
                                                const float* __restrict__ yprob,
                                                const unsigned long long* __restrict__ best,
                                                float* __restrict__ out) {
    __shared__ float P[576 * 17];             // [f][m] stride 17 (bank-spread), 39168B

    int blk = blockIdx.x;                     // 0..1023
    int xcd = blk & 7;
    int n = xcd >> 1;
    int mb = (blk >> 3) + (xcd & 1) * 128;    // 0..255
    int m0 = mb * 16;
    int tid = threadIdx.x;
    int ml = tid >> 4;                        // m_local 0..15
    int cs = (tid & 15) * 4;                  // channel start 0,4,..,60
    int m = m0 + ml;

    unsigned long long key = best[(size_t)n * LL + m];
    unsigned l = 0xFFFFFFFFu - (unsigned)(key & 0xFFFFFFFFull);
    float val = ord2f((unsigned)(key >> 32));
    bool zero = (m == 0);
    if (zero) l = 0;
    int ly = (int)(l >> 6), lx = (int)(l & 63);

    float* Sout = out;                       // [4,1,64,64]
    float* Uout = out + 16384;               // [4,1,64,64]
    float* Rout = out + 32768;               // [4,576,4096]
    float* Aout = out + 9469952;             // [4,4096] as float values

    if (cs == 0) {                            // one thread per m
        float S = zero ? 1e-8f : fminf(fmaxf(val, 1e-8f), 1.0f);
        float U = zero ? 1e-8f : fminf(fmaxf(yprob[(size_t)n * LL + l], 1e-8f), 1.0f);
        Sout[(size_t)n * LL + m] = S;
        Uout[(size_t)n * LL + m] = U;
        Aout[(size_t)n * LL + m] = zero ? -1.0f : (float)l;
    }

    // phase 1: gather 3x3 patch rows channel-contiguous, scatter into LDS [f][m]
    const float* T = yhatT + ((size_t)n * LL) * 64;
#pragma unroll
    for (int i = 0; i < 3; ++i) {
        int yy = ly + i - 1;
        bool rok = (!zero) && (yy >= 0) && (yy < 64);
#pragma unroll
        for (int jj = 0; jj < 3; ++jj) {
            int xx = lx + jj - 1;
            f32x4 v; v.x = 0.f; v.y = 0.f; v.z = 0.f; v.w = 0.f;
            if (rok && xx >= 0 && xx < 64)
                v = *(const f32x4*)(T + ((size_t)(yy * 64 + xx)) * 64 + cs);
            int ij = i * 3 + jj;
            P[((cs + 0) * 9 + ij) * 17 + ml] = v.x;
            P[((cs + 1) * 9 + ij) * 17 + ml] = v.y;
            P[((cs + 2) * 9 + ij) * 17 + ml] = v.z;
            P[((cs + 3) * 9 + ij) * 17 + ml] = v.w;
        }
    }
    __syncthreads();

    // phase 2: coalesced Rout stores (wave = 4 f x 16 m -> 4x64B segments)
    float* R = Rout + (size_t)n * (576 * LL) + m0;
    int fl = tid >> 4;                        // f offset within iteration
    int mm2 = tid & 15;
#pragma unroll 1
    for (int it2 = 0; it2 < 36; ++it2) {
        int f = it2 * 16 + fl;
        float v = P[f * 17 + mm2];
        __builtin_nontemporal_store(v, R + (size_t)f * LL + mm2);
    }
}

extern "C" void kernel_launch(void* const* d_in, const int* in_sizes, int n_in,
                              void* d_out, int out_size, void* d_ws, size_t ws_size,
                              hipStream_t stream) {
    const float* yhat  = (const float*)d_in[0];
    const float* yprob = (const float*)d_in[1];
    float* out = (float*)d_out;

    unsigned short* VhT = (unsigned short*)d_ws;                       // 8 MiB (fragment-packed)
    unsigned short* VlT = (unsigned short*)((char*)d_ws + 8388608);    // 8 MiB (fragment-packed)
    unsigned long long* best =
        (unsigned long long*)((char*)d_ws + 16777216);                 // 128 KiB
    float* yhatT = (float*)((char*)d_ws + 16908288);                   // 4 MiB transpose

    build_v<<<1024, 256, 0, stream>>>(yhat, VhT, VlT, yhatT, best);
    simmax<<<Nn * TRI2, 512, 0, stream>>>(VhT, VlT, best);
    writeout<<<1024, 256, 0, stream>>>(yhatT, yprob, best, out);
}

// Round 11
// 150.374 us; speedup vs baseline: 1.1184x; 1.0003x over previous
//
#include <hip/hip_runtime.h>
#include <stdint.h>

#define Nn 4
#define Cc 64
#define LL 4096   // H*W
#define KK 256    // feature dim: 64 channels * 4 causal taps
#define TRI2 528  // 32*33/2 triangular 128x128 tile pairs per batch

typedef _Float16 half8 __attribute__((ext_vector_type(8)));
typedef float f32x16 __attribute__((ext_vector_type(16)));
typedef float f4a __attribute__((ext_vector_type(4), aligned(4)));
typedef unsigned short ushort8v __attribute__((ext_vector_type(8)));

__device__ __forceinline__ unsigned f2ord(float f) {
    unsigned u = __float_as_uint(f);
    return u ^ ((u & 0x80000000u) ? 0xFFFFFFFFu : 0x80000000u);
}
__device__ __forceinline__ float ord2f(unsigned o) {
    unsigned u = (o & 0x80000000u) ? (o ^ 0x80000000u) : ~o;
    return __uint_as_float(u);
}
__device__ __forceinline__ unsigned short h2u(_Float16 h) {
    union { _Float16 f; unsigned short u; } x; x.f = h; return x.u;
}

// Kernel 1: normalized masked context vectors, split fp16 hi/lo, both pre-scaled:
//   Vh' = 2048*fp16(v)  (exact pow2),  Vl = fp16((v - fp16(v)) * 2048)
// Both MFMA-FRAGMENT-PACKED:
//   addr(n,l,k) = (((n*128+(l>>5))*16+(k>>4))<<9) + ((k>>3)&1)*256 + (l&31)*8 + (k&7)
// XCD-pinned and zeroes its slice of `best`. (yhatT dropped in R11.)
__global__ __launch_bounds__(256) void build_v(const float* __restrict__ yhat,
                                               unsigned short* __restrict__ VhT,
                                               unsigned short* __restrict__ VlT,
                                               unsigned long long* __restrict__ best) {
    int blk = blockIdx.x;                       // 0..1023
    int xcd = blk & 7;
    int n = xcd >> 1;
    int i64 = (blk >> 3) + (xcd & 1) * 128;     // 0..255; block covers l = i64*16 ..+16
    int tid = threadIdx.x;
    if (tid < 16) best[(size_t)n * LL + i64 * 16 + tid] = 0ull;

    int cg = tid & 15;           // channel group 0..15 (4 channels each) == k16 chunk
    int l = i64 * 16 + (tid >> 4);
    int y = l >> 6, x = l & 63;
    const float* src = yhat + (size_t)n * (Cc * LL);

    float vals[16];
    float sumsq = 0.f;
#pragma unroll
    for (int ci = 0; ci < 4; ++ci) {
        const float* p = src + (cg * 4 + ci) * LL;
        float t0 = (y > 0 && x > 0)  ? p[l - 65] : 0.f;
        float t1 = (y > 0)           ? p[l - 64] : 0.f;
        float t2 = (y > 0 && x < 63) ? p[l - 63] : 0.f;
        float t3 = (x > 0)           ? p[l - 1]  : 0.f;
        vals[ci * 4 + 0] = t0; vals[ci * 4 + 1] = t1;
        vals[ci * 4 + 2] = t2; vals[ci * 4 + 3] = t3;
        sumsq += t0 * t0 + t1 * t1 + t2 * t2 + t3 * t3;
    }
    sumsq += __shfl_xor(sumsq, 1, 64);
    sumsq += __shfl_xor(sumsq, 2, 64);
    sumsq += __shfl_xor(sumsq, 4, 64);
    sumsq += __shfl_xor(sumsq, 8, 64);
    float inv = 1.f / fmaxf(sqrtf(sumsq), 1e-12f);

    // fragment-packed destination: 1KB chunk (rowblk,cg) + row slot
    size_t pk = ((((size_t)n * 128 + (l >> 5)) * 16 + cg) << 9) + (l & 31) * 8;
    unsigned short* dh = VhT + pk;
    unsigned short* dl = VlT + pk;
    ushort8v hA, hB, lA, lB;
#pragma unroll
    for (int kk = 0; kk < 16; ++kk) {           // kk = ci*4 + tp = k within chunk
        float v = vals[kk] * inv;
        _Float16 h = (fabsf(v) < 6.1035e-5f) ? (_Float16)0 : (_Float16)v;
        _Float16 lo = (_Float16)((v - (float)h) * 2048.0f);
        unsigned short hu = h2u(h * (_Float16)2048.0f);   // exact pow2 scale
        unsigned short lu = h2u(lo);
        if (kk < 8) { hA[kk] = hu; lA[kk] = lu; }
        else        { hB[kk - 8] = hu; lB[kk - 8] = lu; }
    }
    *(ushort8v*)(dh)       = hA;   // k8-half 0
    *(ushort8v*)(dh + 256) = hB;   // k8-half 1 (+256 halves = +512B)
    *(ushort8v*)(dl)       = lA;
    *(ushort8v*)(dl + 256) = lB;
}

// Kernel 2: triangular 128x128-tiled similarity-max via split-fp16 32x32x16 MFMA.
// acc = Al'Bh' + Ah'Bl + Ah'Bh' = 2^22 * v1.v2 ; val = acc * 2^-22.
// R11: LDS-BANDWIDTH FIX. R10's counters balanced only as an LDS-BW wall:
// 64KB LDS traffic per k16 per block (A chunks re-read 4x, B 2x) vs 192cy MFMA.
// New: HYBRID staging -- A (4x-shared) stays in LDS via glds (ring-2, 32KB);
// B (2x-shared) bypasses LDS: per-wave register loads direct from L2/L1,
// prefetched one k32 phase ahead. LDS traffic 80->48 KB per k32 per block.
// 8 phases (k32 each): barrier{lgkm0,vm4} -> glds A(next) -> load B(next) ->
// ds_read A frags -> 12 MFMA. vmcnt(4) retires exactly the A glds pair from
// the prior phase (4 newer B loads stay in flight); sched_barrier pins
// glds-before-B issue order so the count is exact. Skip waves issue no B
// loads -> they use vmcnt(0) (drains their own glds) -- ledger stays safe.
// 8 waves (512 thr), 64x32/wave, acc 32 AGPR; ~85 VGPR, no spills expected.
// Fragment bytes + per-acc-element MFMA order (p1k0,p1k1,p2k0,p2k1,p3k0,p3k1)
// IDENTICAL to all prior rounds -> bit-exact. Supertile map (R7) kept.
__global__ __launch_bounds__(512) void simmax(const unsigned short* __restrict__ Vh,
                                              const unsigned short* __restrict__ Vl,
                                              unsigned long long* __restrict__ best) {
    __shared__ __align__(16) unsigned short S[16384];   // 2 bufs x 16 A-chunks x 1KB = 32KB

    int bx = blockIdx.x;              // 0..2111
    int xcd = bx & 7, idx = bx >> 3;  // XCD-pin: each XCD owns half of one batch
    int n = xcd >> 1;
    int t = (xcd & 1) * 264 + idx;    // 0..527

    // supertile decode: column J, then off-diag/diag split
    int J = (int)((sqrtf(32.f * (float)t + 4.f) - 2.f) * 0.0625f);
    while (8 * (J + 1) * (J + 1) + 2 * (J + 1) <= t) ++J;
    while (8 * J * J + 2 * J > t) --J;
    int r = t - (8 * J * J + 2 * J);
    int i, j;
    if (r < 16 * J) {                 // off-diagonal supertile (I,J), I<J: 16 tiles
        int I = r >> 4, inner = r & 15;
        i = 4 * I + (inner & 3);
        j = 4 * J + (inner >> 2);
    } else {                          // diagonal supertile (J,J): 10 tiles, di<=dj
        int rr = r - 16 * J;
        int dj = (rr >= 6) ? 3 : (rr >= 3) ? 2 : (rr >= 1) ? 1 : 0;
        int di = rr - ((dj * (dj + 1)) >> 1);
        i = 4 * J + di;
        j = 4 * J + dj;
    }
    int l0 = i * 128, m0 = j * 128;

    int tid = threadIdx.x;
    int w = __builtin_amdgcn_readfirstlane(tid >> 6);   // wave id 0..7 -> SGPR
    int lane = tid & 63;
    int r5 = lane & 31, h5 = lane >> 5;
    int rw = (w & 1) * 64;    // wave rows (l): 0 or 64
    int cw = (w >> 1) * 32;   // wave cols (m): 0,32,64,96
    bool skip = (i == j) && (rw == 64) && (cw < 64);    // fully l>m: no compute

    const unsigned short* VhB = Vh + (size_t)n * (LL * KK);
    const unsigned short* VlB = Vl + (size_t)n * (LL * KK);

    int aRow0 = l0 >> 5;              // block's first A rowblock (of 4)
    int bRow0 = m0 >> 5;              // block's first B rowblock (of 4)

    int laneElem = lane * 8;          // per-lane element offset (16B/lane)

    // A staging: per k32 phase, wave w stages chunks idx = 2w+q (q=0..1):
    // rb = w>>1, lo = w&1, kc = q. Buffer chunk idx = (rb*2+lo)*2+kc = 2w+q.
    const unsigned short* gsrcA[2];
    int lslotA[2];
#pragma unroll
    for (int q = 0; q < 2; ++q) {
        int rb = w >> 1, lo = w & 1;
        gsrcA[q] = (lo ? VlB : VhB) + ((size_t)((aRow0 + rb) * 16 + q) << 9) + laneElem;
        lslotA[q] = (2 * w + q) * 512;
    }
    // B direct-load bases (wave's single B rowblock = bRow0 + (w>>1))
    const unsigned short* pBh = VhB + ((size_t)((bRow0 + (w >> 1)) * 16) << 9) + laneElem;
    const unsigned short* pBl = VlB + ((size_t)((bRow0 + (w >> 1)) * 16) << 9) + laneElem;

    int arb = (w & 1) * 2;            // wave A rowblock base (0 or 2), scalar

    f32x16 acc[2];                    // 32 AGPR
#pragma unroll
    for (int r2 = 0; r2 < 2; ++r2) acc[r2] = (f32x16)0.f;

#define GLDSA(KQ, BN)                                                             \
    do {                                                                          \
        _Pragma("unroll")                                                         \
        for (int q = 0; q < 2; ++q)                                               \
            __builtin_amdgcn_global_load_lds(                                     \
                (const __attribute__((address_space(1))) void*)(gsrcA[q] + (size_t)(KQ) * 1024), \
                (__attribute__((address_space(3))) void*)(S + (BN) * 8192 + lslotA[q]), 16, 0, 0); \
    } while (0)

#define MFMA_SET(AL, AH, BH, BL)                                                  \
    do {                                                                          \
        __builtin_amdgcn_s_setprio(1);                                            \
        _Pragma("unroll")                                                         \
        for (int kc = 0; kc < 2; ++kc)                                            \
            _Pragma("unroll")                                                     \
            for (int r2 = 0; r2 < 2; ++r2)                                        \
                acc[r2] = __builtin_amdgcn_mfma_f32_32x32x16_f16((AL)[r2][kc], (BH)[kc], acc[r2], 0, 0, 0); \
        _Pragma("unroll")                                                         \
        for (int kc = 0; kc < 2; ++kc)                                            \
            _Pragma("unroll")                                                     \
            for (int r2 = 0; r2 < 2; ++r2)                                        \
                acc[r2] = __builtin_amdgcn_mfma_f32_32x32x16_f16((AH)[r2][kc], (BL)[kc], acc[r2], 0, 0, 0); \
        _Pragma("unroll")                                                         \
        for (int kc = 0; kc < 2; ++kc)                                            \
            _Pragma("unroll")                                                     \
            for (int r2 = 0; r2 < 2; ++r2)                                        \
                acc[r2] = __builtin_amdgcn_mfma_f32_32x32x16_f16((AH)[r2][kc], (BH)[kc], acc[r2], 0, 0, 0); \
        __builtin_amdgcn_s_setprio(0);                                            \
    } while (0)

    half8 bhP[2], blP[2], bhQ[2], blQ[2];   // B double-buffer (P = even phases)

    // prologue: stage A(k32=0) -> buf0; load B(0) -> P set
    GLDSA(0, 0);
    __builtin_amdgcn_sched_barrier(0);      // pin glds before B loads (vm order)
    if (!skip) {
        bhP[0] = *(const half8*)(pBh);        bhP[1] = *(const half8*)(pBh + 512);
        blP[0] = *(const half8*)(pBl);        blP[1] = *(const half8*)(pBl + 512);
    }

#pragma unroll
    for (int kq = 0; kq < 8; ++kq) {
        const int cur = (kq & 1) * 8192;
        const bool even = (kq & 1) == 0;

        // barrier: lgkm0 (prev-phase ds_reads drained before buffer reuse);
        // vmcnt(4) retires this phase's A glds (B loads stay in flight).
        // Skip waves issued no B loads -> they must drain fully (vm0).
        if (skip) { asm volatile("s_waitcnt lgkmcnt(0) vmcnt(0)" ::: "memory"); }
        else      { asm volatile("s_waitcnt lgkmcnt(0) vmcnt(4)" ::: "memory"); }
        __builtin_amdgcn_s_barrier();
        __builtin_amdgcn_sched_barrier(0);

        if (kq < 7) {
            GLDSA(kq + 1, (kq + 1) & 1);
            __builtin_amdgcn_sched_barrier(0);  // keep glds ahead of B loads
            if (!skip) {
                const unsigned short* nh = pBh + (size_t)(kq + 1) * 1024;
                const unsigned short* nl = pBl + (size_t)(kq + 1) * 1024;
                if (even) {
                    bhQ[0] = *(const half8*)(nh);       bhQ[1] = *(const half8*)(nh + 512);
                    blQ[0] = *(const half8*)(nl);       blQ[1] = *(const half8*)(nl + 512);
                } else {
                    bhP[0] = *(const half8*)(nh);       bhP[1] = *(const half8*)(nh + 512);
                    blP[0] = *(const half8*)(nl);       blP[1] = *(const half8*)(nl + 512);
                }
            }
        }

        if (!skip) {
            half8 al[2][2], ah[2][2];
#pragma unroll
            for (int kc = 0; kc < 2; ++kc)
#pragma unroll
                for (int r2 = 0; r2 < 2; ++r2) {
                    al[r2][kc] = *(const half8*)(S + cur + (((arb + r2) * 2 + 1) * 2 + kc) * 512 + laneElem);
                    ah[r2][kc] = *(const half8*)(S + cur + (((arb + r2) * 2) * 2 + kc) * 512 + laneElem);
                }
            if (even) MFMA_SET(al, ah, bhP, blP);
            else      MFMA_SET(al, ah, bhQ, blQ);
        }
    }
#undef GLDSA
#undef MFMA_SET

    if (skip) return;
    unsigned long long* bb = best + (size_t)n * LL;
    const float s = 1.f / 4194304.f;   // 2^-22
    {
        int m = m0 + cw + r5;
        unsigned long long key = 0ull;
#pragma unroll
        for (int r2 = 0; r2 < 2; ++r2)
#pragma unroll
            for (int g = 0; g < 16; ++g) {
                int l = l0 + rw + r2 * 32 + (g & 3) + 8 * (g >> 2) + 4 * h5;
                if (l < m) {
                    float v = acc[r2][g] * s;
                    unsigned long long k2 =
                        ((unsigned long long)f2ord(v) << 32) |
                        (unsigned long long)(0xFFFFFFFFu - (unsigned)l);
                    key = (k2 > key) ? k2 : key;
                }
            }
        unsigned long long o = __shfl_xor(key, 32, 64);
        key = (o > key) ? o : key;
        if (h5 == 0 && key != 0ull) atomicMax(bb + m, key);
    }
}

// Kernel 3 (reverted to the R0-proven form): unpack best, write S, U,
// ref_unfold, arg (float values), m==0 overrides.
// 4096 blocks (16 channel-groups of 4) for TLP; XCD-pinned per batch.
__global__ __launch_bounds__(256) void writeout(const float* __restrict__ yhat,
                                                const float* __restrict__ yprob,
                                                const unsigned long long* __restrict__ best,
                                                float* __restrict__ out) {
    int blk = blockIdx.x;                     // 0..4095
    int xcd = blk & 7;
    int n = xcd >> 1;
    int idx = (blk >> 3) + (xcd & 1) * 512;   // 0..1023
    int mb = idx >> 4;                        // 0..63
    int fc = idx & 15;                        // channel group of 4
    int tid = threadIdx.x;
    int mm = tid & 63;
    int fs = tid >> 6;                        // 0..3
    int c = fc * 4 + fs;
    int m = mb * 64 + mm;

    unsigned long long key = best[(size_t)n * LL + m];
    unsigned l = 0xFFFFFFFFu - (unsigned)(key & 0xFFFFFFFFull);
    float val = ord2f((unsigned)(key >> 32));
    bool zero = (m == 0);
    if (zero) l = 0;
    int ly = (int)(l >> 6), lx = (int)(l & 63);

    float* Sout = out;                       // [4,1,64,64]
    float* Uout = out + 16384;               // [4,1,64,64]
    float* Rout = out + 32768;               // [4,576,4096]
    float* Aout = out + 9469952;             // [4,4096] as float values

    if (fc == 0 && fs == 0) {
        float S = zero ? 1e-8f : fminf(fmaxf(val, 1e-8f), 1.0f);
        float U = zero ? 1e-8f : fminf(fmaxf(yprob[(size_t)n * LL + l], 1e-8f), 1.0f);
        Sout[(size_t)n * LL + m] = S;
        Uout[(size_t)n * LL + m] = U;
        Aout[(size_t)n * LL + m] = zero ? -1.0f : (float)l;
    }

    const float* src = yhat + (size_t)n * (Cc * LL);
    const float* plane = src + (size_t)c * LL;
    float* dst = Rout + (size_t)n * (576 * LL) + m;
    bool fast = (!zero) && (lx >= 1) && (lx <= 61);
#pragma unroll
    for (int r3 = 0; r3 < 3; ++r3) {
        int yy = ly + r3 - 1;
        bool rowok = (!zero) && (yy >= 0) && (yy < 64);
        float t0 = 0.f, t1 = 0.f, t2 = 0.f;
        if (rowok) {
            if (fast) {
                f4a v = *(const f4a*)(plane + yy * 64 + lx - 1);
                t0 = v.x; t1 = v.y; t2 = v.z;
            } else {
                if (lx > 0)  t0 = plane[yy * 64 + lx - 1];
                t1 = plane[yy * 64 + lx];
                if (lx < 63) t2 = plane[yy * 64 + lx + 1];
            }
        }
        size_t f = (size_t)(c * 9 + r3 * 3) * LL;
        __builtin_nontemporal_store(t0, dst + f);
        __builtin_nontemporal_store(t1, dst + f + LL);
        __builtin_nontemporal_store(t2, dst + f + 2 * (size_t)LL);
    }
}

extern "C" void kernel_launch(void* const* d_in, const int* in_sizes, int n_in,
                              void* d_out, int out_size, void* d_ws, size_t ws_size,
                              hipStream_t stream) {
    const float* yhat  = (const float*)d_in[0];
    const float* yprob = (const float*)d_in[1];
    float* out = (float*)d_out;

    unsigned short* VhT = (unsigned short*)d_ws;                       // 8 MiB (fragment-packed)
    unsigned short* VlT = (unsigned short*)((char*)d_ws + 8388608);    // 8 MiB (fragment-packed)
    unsigned long long* best =
        (unsigned long long*)((char*)d_ws + 16777216);                 // 128 KiB

    build_v<<<1024, 256, 0, stream>>>(yhat, VhT, VlT, best);
    simmax<<<Nn * TRI2, 512, 0, stream>>>(VhT, VlT, best);
    writeout<<<4096, 256, 0, stream>>>(yhat, yprob, best, out);
}

// Round 12
// 148.898 us; speedup vs baseline: 1.1295x; 1.0099x over previous
//
#include <hip/hip_runtime.h>
#include <stdint.h>

#define Nn 4
#define Cc 64
#define LL 4096   // H*W
#define KK 256    // feature dim: 64 channels * 4 causal taps
#define TRI2 528  // 32*33/2 triangular 128x128 tile pairs per batch

typedef _Float16 half8 __attribute__((ext_vector_type(8)));
typedef float f32x16 __attribute__((ext_vector_type(16)));
typedef float f4a __attribute__((ext_vector_type(4), aligned(4)));
typedef unsigned short ushort8v __attribute__((ext_vector_type(8)));

__device__ __forceinline__ unsigned f2ord(float f) {
    unsigned u = __float_as_uint(f);
    return u ^ ((u & 0x80000000u) ? 0xFFFFFFFFu : 0x80000000u);
}
__device__ __forceinline__ float ord2f(unsigned o) {
    unsigned u = (o & 0x80000000u) ? (o ^ 0x80000000u) : ~o;
    return __uint_as_float(u);
}
__device__ __forceinline__ unsigned short h2u(_Float16 h) {
    union { _Float16 f; unsigned short u; } x; x.f = h; return x.u;
}

// Ring-2 phase barrier (1 per k32 phase): lgkm0 drains my previous-phase
// ds_reads (buffer about to be overwritten), vm0 retires my glds batch for
// the buffer about to be READ (issued one full phase earlier -> wait ~free).
// s_barrier then makes all waves' staged chunks visible.
__device__ __forceinline__ void pipe_barrier() {
    asm volatile("s_waitcnt lgkmcnt(0) vmcnt(0)" ::: "memory");
    __builtin_amdgcn_s_barrier();
    __builtin_amdgcn_sched_barrier(0);
}

// Kernel 1: normalized masked context vectors, split fp16 hi/lo, both pre-scaled:
//   Vh' = 2048*fp16(v)  (exact pow2),  Vl = fp16((v - fp16(v)) * 2048)
// Both MFMA-FRAGMENT-PACKED:
//   addr(n,l,k) = (((n*128+(l>>5))*16+(k>>4))<<9) + ((k>>3)&1)*256 + (l&31)*8 + (k&7)
// XCD-pinned and zeroes its slice of `best`.
__global__ __launch_bounds__(256) void build_v(const float* __restrict__ yhat,
                                               unsigned short* __restrict__ VhT,
                                               unsigned short* __restrict__ VlT,
                                               unsigned long long* __restrict__ best) {
    int blk = blockIdx.x;                       // 0..1023
    int xcd = blk & 7;
    int n = xcd >> 1;
    int i64 = (blk >> 3) + (xcd & 1) * 128;     // 0..255; block covers l = i64*16 ..+16
    int tid = threadIdx.x;
    if (tid < 16) best[(size_t)n * LL + i64 * 16 + tid] = 0ull;

    int cg = tid & 15;           // channel group 0..15 (4 channels each) == k16 chunk
    int l = i64 * 16 + (tid >> 4);
    int y = l >> 6, x = l & 63;
    const float* src = yhat + (size_t)n * (Cc * LL);

    float vals[16];
    float sumsq = 0.f;
#pragma unroll
    for (int ci = 0; ci < 4; ++ci) {
        const float* p = src + (cg * 4 + ci) * LL;
        float t0 = (y > 0 && x > 0)  ? p[l - 65] : 0.f;
        float t1 = (y > 0)           ? p[l - 64] : 0.f;
        float t2 = (y > 0 && x < 63) ? p[l - 63] : 0.f;
        float t3 = (x > 0)           ? p[l - 1]  : 0.f;
        vals[ci * 4 + 0] = t0; vals[ci * 4 + 1] = t1;
        vals[ci * 4 + 2] = t2; vals[ci * 4 + 3] = t3;
        sumsq += t0 * t0 + t1 * t1 + t2 * t2 + t3 * t3;
    }
    sumsq += __shfl_xor(sumsq, 1, 64);
    sumsq += __shfl_xor(sumsq, 2, 64);
    sumsq += __shfl_xor(sumsq, 4, 64);
    sumsq += __shfl_xor(sumsq, 8, 64);
    float inv = 1.f / fmaxf(sqrtf(sumsq), 1e-12f);

    // fragment-packed destination: 1KB chunk (rowblk,cg) + row slot
    size_t pk = ((((size_t)n * 128 + (l >> 5)) * 16 + cg) << 9) + (l & 31) * 8;
    unsigned short* dh = VhT + pk;
    unsigned short* dl = VlT + pk;
    ushort8v hA, hB, lA, lB;
#pragma unroll
    for (int kk = 0; kk < 16; ++kk) {           // kk = ci*4 + tp = k within chunk
        float v = vals[kk] * inv;
        _Float16 h = (fabsf(v) < 6.1035e-5f) ? (_Float16)0 : (_Float16)v;
        _Float16 lo = (_Float16)((v - (float)h) * 2048.0f);
        unsigned short hu = h2u(h * (_Float16)2048.0f);   // exact pow2 scale
        unsigned short lu = h2u(lo);
        if (kk < 8) { hA[kk] = hu; lA[kk] = lu; }
        else        { hB[kk - 8] = hu; lB[kk - 8] = lu; }
    }
    *(ushort8v*)(dh)       = hA;   // k8-half 0
    *(ushort8v*)(dh + 256) = hB;   // k8-half 1 (+256 halves = +512B)
    *(ushort8v*)(dl)       = lA;
    *(ushort8v*)(dl + 256) = lB;
}

// Kernel 2: triangular 128x128-tiled similarity-max via split-fp16 32x32x16 MFMA.
// acc = Al'Bh' + Ah'Bl + Ah'Bh' = 2^22 * v1.v2 ; val = acc * 2^-22.
// R12: HIGH-OCC x FEW-BARRIER combo (never tested jointly). 8-wave (512 thr)
// shape at ~107 combined regs + k32 phases + ring-2 x 32KB (64KB LDS) ->
// 2 blocks/CU x 8 waves = 16 waves/CU (50%), 4 waves/SIMD, only 8 barriers
// per tile with 24 MFMA per wave per interval (vs R10's 16 barriers / 12 MFMA
// at 33% occ; vs R4's 8 barriers at 25% occ). One lgkm0+vm0 barrier per phase
// (glds issued one full phase ahead -> vm0 ~free). Full A+B staging (R11's
// B-bypass regressed). Supertile map (R7) kept.
// Buffer: 32 chunks x 1KB; chunk c: side=c>>4, rb=(c>>2)&3, lo=(c>>1)&1, kc=c&1.
// Wave w stages c = 4w+q. Fragment bytes + per-acc-element MFMA order
// (p1k0,p1k1,p2k0,p2k1,p3k0,p3k1) IDENTICAL to all prior rounds -> bit-exact.
__global__ __launch_bounds__(512) void simmax(const unsigned short* __restrict__ Vh,
                                              const unsigned short* __restrict__ Vl,
                                              unsigned long long* __restrict__ best) {
    __shared__ __align__(16) unsigned short S[32768];   // 2 bufs x 32 chunks x 1KB = 64KB

    int bx = blockIdx.x;              // 0..2111
    int xcd = bx & 7, idx = bx >> 3;  // XCD-pin: each XCD owns half of one batch
    int n = xcd >> 1;
    int t = (xcd & 1) * 264 + idx;    // 0..527

    // supertile decode: column J, then off-diag/diag split
    int J = (int)((sqrtf(32.f * (float)t + 4.f) - 2.f) * 0.0625f);
    while (8 * (J + 1) * (J + 1) + 2 * (J + 1) <= t) ++J;
    while (8 * J * J + 2 * J > t) --J;
    int r = t - (8 * J * J + 2 * J);
    int i, j;
    if (r < 16 * J) {                 // off-diagonal supertile (I,J), I<J: 16 tiles
        int I = r >> 4, inner = r & 15;
        i = 4 * I + (inner & 3);
        j = 4 * J + (inner >> 2);
    } else {                          // diagonal supertile (J,J): 10 tiles, di<=dj
        int rr = r - 16 * J;
        int dj = (rr >= 6) ? 3 : (rr >= 3) ? 2 : (rr >= 1) ? 1 : 0;
        int di = rr - ((dj * (dj + 1)) >> 1);
        i = 4 * J + di;
        j = 4 * J + dj;
    }
    int l0 = i * 128, m0 = j * 128;

    int tid = threadIdx.x;
    int w = __builtin_amdgcn_readfirstlane(tid >> 6);   // wave id 0..7 -> SGPR
    int lane = tid & 63;
    int r5 = lane & 31, h5 = lane >> 5;
    int rw = (w & 1) * 64;    // wave rows (l): 0 or 64
    int cw = (w >> 1) * 32;   // wave cols (m): 0,32,64,96
    bool skip = (i == j) && (rw == 64) && (cw < 64);    // fully l>m: no compute

    const unsigned short* VhB = Vh + (size_t)n * (LL * KK);
    const unsigned short* VlB = Vl + (size_t)n * (LL * KK);

    int aRow0 = l0 >> 5;              // block's first A rowblock (of 4)
    int bRow0 = m0 >> 5;              // block's first B rowblock (of 4)

    int laneElem = lane * 8;          // per-lane element offset (16B/lane)

    // staging: per k32 phase, wave w stages chunks c = 4w+q (q=0..3)
    const unsigned short* gsrc[4];
    int lslot[4];
#pragma unroll
    for (int q = 0; q < 4; ++q) {
        int c = w * 4 + q;                          // scalar
        int side = c >> 4, rb = (c >> 2) & 3, lo = (c >> 1) & 1, kc = c & 1;
        int rowblk = (side ? bRow0 : aRow0) + rb;
        gsrc[q] = (lo ? VlB : VhB) + (((size_t)(rowblk * 16) + kc) << 9) + laneElem;
        lslot[q] = c * 512;                         // scalar
    }

    int arb = (w & 1) * 2;            // wave A rowblock base (0 or 2), scalar
    int brb = (w >> 1);               // wave B rowblock (0..3), scalar

    f32x16 acc[2];                    // 32 AGPR
#pragma unroll
    for (int r2 = 0; r2 < 2; ++r2) acc[r2] = (f32x16)0.f;

    // chunk offsets (halves) within a buffer for this wave's fragments
    // al: chunk (arb+r2)*4 + 2 + kc ; ah: (arb+r2)*4 + kc
    // bh: 16 + brb*4 + kc ; bl: 16 + brb*4 + 2 + kc
#define GLDS(PH, BN)                                                              \
    do {                                                                          \
        _Pragma("unroll")                                                         \
        for (int q = 0; q < 4; ++q)                                               \
            __builtin_amdgcn_global_load_lds(                                     \
                (const __attribute__((address_space(1))) void*)(gsrc[q] + (size_t)(PH) * 1024), \
                (__attribute__((address_space(3))) void*)(S + (BN) * 16384 + lslot[q]), 16, 0, 0); \
    } while (0)

    // prologue: stage phase 0 -> buf0 (4 glds in flight)
    GLDS(0, 0);

#pragma unroll
    for (int p = 0; p < 8; ++p) {
        const int cur = (p & 1) * 16384;

        // one barrier per k32 phase
        pipe_barrier();
        if (p < 7) GLDS(p + 1, (p + 1) & 1);

        if (!skip) {
            half8 al[2][2], ah[2][2], bh[2], bl[2];
#pragma unroll
            for (int kc = 0; kc < 2; ++kc) {
#pragma unroll
                for (int r2 = 0; r2 < 2; ++r2) {
                    al[r2][kc] = *(const half8*)(S + cur + ((arb + r2) * 4 + 2 + kc) * 512 + laneElem);
                    ah[r2][kc] = *(const half8*)(S + cur + ((arb + r2) * 4 + kc) * 512 + laneElem);
                }
                bh[kc] = *(const half8*)(S + cur + (16 + brb * 4 + kc) * 512 + laneElem);
                bl[kc] = *(const half8*)(S + cur + (16 + brb * 4 + 2 + kc) * 512 + laneElem);
            }
            __builtin_amdgcn_s_setprio(1);
            // pass1: Al*Bh (kc0,kc1) ; pass2: Ah*Bl ; pass3: Ah*Bh -- exact order
#pragma unroll
            for (int kc = 0; kc < 2; ++kc)
#pragma unroll
                for (int r2 = 0; r2 < 2; ++r2)
                    acc[r2] = __builtin_amdgcn_mfma_f32_32x32x16_f16(al[r2][kc], bh[kc], acc[r2], 0, 0, 0);
#pragma unroll
            for (int kc = 0; kc < 2; ++kc)
#pragma unroll
                for (int r2 = 0; r2 < 2; ++r2)
                    acc[r2] = __builtin_amdgcn_mfma_f32_32x32x16_f16(ah[r2][kc], bl[kc], acc[r2], 0, 0, 0);
#pragma unroll
            for (int kc = 0; kc < 2; ++kc)
#pragma unroll
                for (int r2 = 0; r2 < 2; ++r2)
                    acc[r2] = __builtin_amdgcn_mfma_f32_32x32x16_f16(ah[r2][kc], bh[kc], acc[r2], 0, 0, 0);
            __builtin_amdgcn_s_setprio(0);
        }
    }
#undef GLDS

    if (skip) return;
    unsigned long long* bb = best + (size_t)n * LL;
    const float s = 1.f / 4194304.f;   // 2^-22
    {
        int m = m0 + cw + r5;
        unsigned long long key = 0ull;
#pragma unroll
        for (int r2 = 0; r2 < 2; ++r2)
#pragma unroll
            for (int g = 0; g < 16; ++g) {
                int l = l0 + rw + r2 * 32 + (g & 3) + 8 * (g >> 2) + 4 * h5;
                if (l < m) {
                    float v = acc[r2][g] * s;
                    unsigned long long k2 =
                        ((unsigned long long)f2ord(v) << 32) |
                        (unsigned long long)(0xFFFFFFFFu - (unsigned)l);
                    key = (k2 > key) ? k2 : key;
                }
            }
        unsigned long long o = __shfl_xor(key, 32, 64);
        key = (o > key) ? o : key;
        if (h5 == 0 && key != 0ull) atomicMax(bb + m, key);
    }
}

// Kernel 3: unpack best, write S, U, ref_unfold, arg (float values), m==0
// overrides. 4096 blocks (16 channel-groups of 4) for TLP; XCD-pinned per batch.
__global__ __launch_bounds__(256) void writeout(const float* __restrict__ yhat,
                                                const float* __restrict__ yprob,
                                                const unsigned long long* __restrict__ best,
                                                float* __restrict__ out) {
    int blk = blockIdx.x;                     // 0..4095
    int xcd = blk & 7;
    int n = xcd >> 1;
    int idx = (blk >> 3) + (xcd & 1) * 512;   // 0..1023
    int mb = idx >> 4;                        // 0..63
    int fc = idx & 15;                        // channel group of 4
    int tid = threadIdx.x;
    int mm = tid & 63;
    int fs = tid >> 6;                        // 0..3
    int c = fc * 4 + fs;
    int m = mb * 64 + mm;

    unsigned long long key = best[(size_t)n * LL + m];
    unsigned l = 0xFFFFFFFFu - (unsigned)(key & 0xFFFFFFFFull);
    float val = ord2f((unsigned)(key >> 32));
    bool zero = (m == 0);
    if (zero) l = 0;
    int ly = (int)(l >> 6), lx = (int)(l & 63);

    float* Sout = out;                       // [4,1,64,64]
    float* Uout = out + 16384;               // [4,1,64,64]
    float* Rout = out + 32768;               // [4,576,4096]
    float* Aout = out + 9469952;             // [4,4096] as float values

    if (fc == 0 && fs == 0) {
        float S = zero ? 1e-8f : fminf(fmaxf(val, 1e-8f), 1.0f);
        float U = zero ? 1e-8f : fminf(fmaxf(yprob[(size_t)n * LL + l], 1e-8f), 1.0f);
        Sout[(size_t)n * LL + m] = S;
        Uout[(size_t)n * LL + m] = U;
        Aout[(size_t)n * LL + m] = zero ? -1.0f : (float)l;
    }

    const float* src = yhat + (size_t)n * (Cc * LL);
    const float* plane = src + (size_t)c * LL;
    float* dst = Rout + (size_t)n * (576 * LL) + m;
    bool fast = (!zero) && (lx >= 1) && (lx <= 61);
#pragma unroll
    for (int r3 = 0; r3 < 3; ++r3) {
        int yy = ly + r3 - 1;
        bool rowok = (!zero) && (yy >= 0) && (yy < 64);
        float t0 = 0.f, t1 = 0.f, t2 = 0.f;
        if (rowok) {
            if (fast) {
                f4a v = *(const f4a*)(plane + yy * 64 + lx - 1);
                t0 = v.x; t1 = v.y; t2 = v.z;
            } else {
                if (lx > 0)  t0 = plane[yy * 64 + lx - 1];
                t1 = plane[yy * 64 + lx];
                if (lx < 63) t2 = plane[yy * 64 + lx + 1];
            }
        }
        size_t f = (size_t)(c * 9 + r3 * 3) * LL;
        __builtin_nontemporal_store(t0, dst + f);
        __builtin_nontemporal_store(t1, dst + f + LL);
        __builtin_nontemporal_store(t2, dst + f + 2 * (size_t)LL);
    }
}

extern "C" void kernel_launch(void* const* d_in, const int* in_sizes, int n_in,
                              void* d_out, int out_size, void* d_ws, size_t ws_size,
                              hipStream_t stream) {
    const float* yhat  = (const float*)d_in[0];
    const float* yprob = (const float*)d_in[1];
    float* out = (float*)d_out;

    unsigned short* VhT = (unsigned short*)d_ws;                       // 8 MiB (fragment-packed)
    unsigned short* VlT = (unsigned short*)((char*)d_ws + 8388608);    // 8 MiB (fragment-packed)
    unsigned long long* best =
        (unsigned long long*)((char*)d_ws + 16777216);                 // 128 KiB

    build_v<<<1024, 256, 0, stream>>>(yhat, VhT, VlT, best);
    simmax<<<Nn * TRI2, 512, 0, stream>>>(VhT, VlT, best);
    writeout<<<4096, 256, 0, stream>>>(yhat, yprob, best, out);
}

// Round 13
// 147.016 us; speedup vs baseline: 1.1439x; 1.0128x over previous
//
#include <hip/hip_runtime.h>
#include <stdint.h>

#define Nn 4
#define Cc 64
#define LL 4096   // H*W
#define KK 256    // feature dim: 64 channels * 4 causal taps
#define TRI2 528  // 32*33/2 triangular 128x128 tile pairs per batch

typedef _Float16 half8 __attribute__((ext_vector_type(8)));
typedef float f32x16 __attribute__((ext_vector_type(16)));
typedef float f4a __attribute__((ext_vector_type(4), aligned(4)));
typedef unsigned short ushort8v __attribute__((ext_vector_type(8)));

__device__ __forceinline__ unsigned f2ord(float f) {
    unsigned u = __float_as_uint(f);
    return u ^ ((u & 0x80000000u) ? 0xFFFFFFFFu : 0x80000000u);
}
__device__ __forceinline__ float ord2f(unsigned o) {
    unsigned u = (o & 0x80000000u) ? (o ^ 0x80000000u) : ~o;
    return __uint_as_float(u);
}
__device__ __forceinline__ unsigned short h2u(_Float16 h) {
    union { _Float16 f; unsigned short u; } x; x.f = h; return x.u;
}

// Raw barrier with COUNTED vmcnt (T4, m201-template pattern): the newest
// glds batches stay in flight across the barrier; only older batches are
// guaranteed landed. lgkmcnt(0) before s_barrier closes the LDS
// read-before-overwrite hazard.
__device__ __forceinline__ void pipe_barrier_vm4() {
    asm volatile("s_waitcnt lgkmcnt(0) vmcnt(4)" ::: "memory");
    __builtin_amdgcn_s_barrier();
    __builtin_amdgcn_sched_barrier(0);
}
__device__ __forceinline__ void pipe_barrier_vm0() {
    asm volatile("s_waitcnt lgkmcnt(0) vmcnt(0)" ::: "memory");
    __builtin_amdgcn_s_barrier();
    __builtin_amdgcn_sched_barrier(0);
}

// Kernel 1: normalized masked context vectors, split fp16 hi/lo, both pre-scaled:
//   Vh' = 2048*fp16(v)  (exact pow2),  Vl = fp16((v - fp16(v)) * 2048)
// Both MFMA-FRAGMENT-PACKED:
//   addr(n,l,k) = (((n*128+(l>>5))*16+(k>>4))<<9) + ((k>>3)&1)*256 + (l&31)*8 + (k&7)
// XCD-pinned and zeroes its slice of `best`.
__global__ __launch_bounds__(256) void build_v(const float* __restrict__ yhat,
                                               unsigned short* __restrict__ VhT,
                                               unsigned short* __restrict__ VlT,
                                               unsigned long long* __restrict__ best) {
    int blk = blockIdx.x;                       // 0..1023
    int xcd = blk & 7;
    int n = xcd >> 1;
    int i64 = (blk >> 3) + (xcd & 1) * 128;     // 0..255; block covers l = i64*16 ..+16
    int tid = threadIdx.x;
    if (tid < 16) best[(size_t)n * LL + i64 * 16 + tid] = 0ull;

    int cg = tid & 15;           // channel group 0..15 (4 channels each) == k16 chunk
    int l = i64 * 16 + (tid >> 4);
    int y = l >> 6, x = l & 63;
    const float* src = yhat + (size_t)n * (Cc * LL);

    float vals[16];
    float sumsq = 0.f;
#pragma unroll
    for (int ci = 0; ci < 4; ++ci) {
        const float* p = src + (cg * 4 + ci) * LL;
        float t0 = (y > 0 && x > 0)  ? p[l - 65] : 0.f;
        float t1 = (y > 0)           ? p[l - 64] : 0.f;
        float t2 = (y > 0 && x < 63) ? p[l - 63] : 0.f;
        float t3 = (x > 0)           ? p[l - 1]  : 0.f;
        vals[ci * 4 + 0] = t0; vals[ci * 4 + 1] = t1;
        vals[ci * 4 + 2] = t2; vals[ci * 4 + 3] = t3;
        sumsq += t0 * t0 + t1 * t1 + t2 * t2 + t3 * t3;
    }
    sumsq += __shfl_xor(sumsq, 1, 64);
    sumsq += __shfl_xor(sumsq, 2, 64);
    sumsq += __shfl_xor(sumsq, 4, 64);
    sumsq += __shfl_xor(sumsq, 8, 64);
    float inv = 1.f / fmaxf(sqrtf(sumsq), 1e-12f);

    // fragment-packed destination: 1KB chunk (rowblk,cg) + row slot
    size_t pk = ((((size_t)n * 128 + (l >> 5)) * 16 + cg) << 9) + (l & 31) * 8;
    unsigned short* dh = VhT + pk;
    unsigned short* dl = VlT + pk;
    ushort8v hA, hB, lA, lB;
#pragma unroll
    for (int kk = 0; kk < 16; ++kk) {           // kk = ci*4 + tp = k within chunk
        float v = vals[kk] * inv;
        _Float16 h = (fabsf(v) < 6.1035e-5f) ? (_Float16)0 : (_Float16)v;
        _Float16 lo = (_Float16)((v - (float)h) * 2048.0f);
        unsigned short hu = h2u(h * (_Float16)2048.0f);   // exact pow2 scale
        unsigned short lu = h2u(lo);
        if (kk < 8) { hA[kk] = hu; lA[kk] = lu; }
        else        { hB[kk - 8] = hu; lB[kk - 8] = lu; }
    }
    *(ushort8v*)(dh)       = hA;   // k8-half 0
    *(ushort8v*)(dh + 256) = hB;   // k8-half 1 (+256 halves = +512B)
    *(ushort8v*)(dl)       = lA;
    *(ushort8v*)(dl + 256) = lB;
}

// Kernel 2 (R7-proven, 60.0us): triangular 128x128-tiled similarity-max via
// split-fp16 32x32x16 MFMA. acc = Al'Bh' + Ah'Bl + Ah'Bh' = 2^22 * v1.v2.
// k16-granular staging into a RING of 3 x 16KB LDS buffers via global_load_lds;
// 16 phases with counted-vmcnt raw barriers; SUPERTILE tile->block mapping for
// per-XCD L2 locality. 4 waves (256 thr), 64x64 per wave. Fragment bytes and
// per-acc-element accumulation order (p1k0,p1k1,p2k0,p2k1,p3k0,p3k1) are
// bit-identical to every verified round -> absmax stays 0.
__global__ __launch_bounds__(256) void simmax(const unsigned short* __restrict__ Vh,
                                              const unsigned short* __restrict__ Vl,
                                              unsigned long long* __restrict__ best) {
    __shared__ __align__(16) unsigned short S[24576];   // 3 bufs x 16 chunks x 1KB = 48KB

    int bx = blockIdx.x;              // 0..2111
    int xcd = bx & 7, idx = bx >> 3;  // XCD-pin: each XCD owns half of one batch
    int n = xcd >> 1;
    int t = (xcd & 1) * 264 + idx;    // 0..527

    // supertile decode: column J, then off-diag/diag split
    int J = (int)((sqrtf(32.f * (float)t + 4.f) - 2.f) * 0.0625f);
    while (8 * (J + 1) * (J + 1) + 2 * (J + 1) <= t) ++J;
    while (8 * J * J + 2 * J > t) --J;
    int r = t - (8 * J * J + 2 * J);
    int i, j;
    if (r < 16 * J) {                 // off-diagonal supertile (I,J), I<J: 16 tiles
        int I = r >> 4, inner = r & 15;
        i = 4 * I + (inner & 3);
        j = 4 * J + (inner >> 2);
    } else {                          // diagonal supertile (J,J): 10 tiles, di<=dj
        int rr = r - 16 * J;
        int dj = (rr >= 6) ? 3 : (rr >= 3) ? 2 : (rr >= 1) ? 1 : 0;
        int di = rr - ((dj * (dj + 1)) >> 1);
        i = 4 * J + di;
        j = 4 * J + dj;
    }
    int l0 = i * 128, m0 = j * 128;

    int tid = threadIdx.x;
    int w = tid >> 6, lane = tid & 63;
    int r5 = lane & 31, h5 = lane >> 5;
    int rw = (w & 1) * 64;    // wave rows (l)
    int cw = (w >> 1) * 64;   // wave cols (m)
    bool skip = (i == j) && (rw == 64) && (cw == 0);  // fully l>m: no compute

    const unsigned short* VhB = Vh + (size_t)n * (LL * KK);
    const unsigned short* VlB = Vl + (size_t)n * (LL * KK);

    int aRow0 = l0 >> 5;              // block's first A rowblock (of 4)
    int bRow0 = m0 >> 5;              // block's first B rowblock (of 4)

    // staging: per k16 phase, wave w stages chunk idx = w*4+q (q=0..3)
    const unsigned short* gsrc[4];
    int lslot[4];
#pragma unroll
    for (int q = 0; q < 4; ++q) {
        int cidx = w * 4 + q;
        int side = cidx >> 3, rb = (cidx >> 1) & 3, lo = cidx & 1;
        int rowblk = (side ? bRow0 : aRow0) + rb;
        gsrc[q] = (lo ? VlB : VhB) + ((size_t)(rowblk * 16) << 9) + lane * 8;
        lslot[q] = cidx * 512;
    }

    int arb = (w & 1) * 2;            // wave A rowblock base (0 or 2)
    int brb = (w >> 1) * 2;           // wave B rowblock base

    f32x16 acc[2][2];
#pragma unroll
    for (int r2 = 0; r2 < 2; ++r2)
#pragma unroll
        for (int c = 0; c < 2; ++c) acc[r2][c] = (f32x16)0.f;

#define GLDS(KQ, BN)                                                              \
    do {                                                                          \
        _Pragma("unroll")                                                         \
        for (int q = 0; q < 4; ++q)                                               \
            __builtin_amdgcn_global_load_lds(                                     \
                (const __attribute__((address_space(1))) void*)(gsrc[q] + (size_t)(KQ) * 512), \
                (__attribute__((address_space(3))) void*)(S + (BN) * 8192 + lslot[q]), 16, 0, 0); \
    } while (0)

    // prologue: stage k16=0 -> buf0, k16=1 -> buf1 (8 glds in flight)
    GLDS(0, 0);
    GLDS(1, 1);

#pragma unroll
    for (int kt = 0; kt < 8; ++kt) {
        const int b0 = (2 * kt) % 3;       // buffer holding kc0 (k16 = 2kt)
        const int b1 = (2 * kt + 1) % 3;   // buffer holding kc1

        half8 al[2][2], ah[2][2], bl[2][2], bh[2][2];

        // ---- phase A: barrier (k16=2kt landed; frees buf (2kt+2)%3),
        //      stage k16=2kt+2, read kc0 frags, pass1-kc0 MFMAs
        pipe_barrier_vm4();
        if (kt < 7) GLDS(2 * kt + 2, (2 * kt + 2) % 3);
        if (!skip) {
#pragma unroll
            for (int r2 = 0; r2 < 2; ++r2) {
                al[r2][0] = *(const half8*)(S + b0 * 8192 + ((arb + r2) * 2 + 1) * 512 + lane * 8);
                bh[r2][0] = *(const half8*)(S + b0 * 8192 + (8 + (brb + r2) * 2) * 512 + lane * 8);
            }
#pragma unroll
            for (int r2 = 0; r2 < 2; ++r2) {
                ah[r2][0] = *(const half8*)(S + b0 * 8192 + ((arb + r2) * 2) * 512 + lane * 8);
                bl[r2][0] = *(const half8*)(S + b0 * 8192 + (9 + (brb + r2) * 2) * 512 + lane * 8);
            }
            __builtin_amdgcn_s_setprio(1);
#pragma unroll
            for (int r2 = 0; r2 < 2; ++r2)
#pragma unroll
                for (int c = 0; c < 2; ++c)
                    acc[r2][c] = __builtin_amdgcn_mfma_f32_32x32x16_f16(al[r2][0], bh[c][0], acc[r2][c], 0, 0, 0);
            __builtin_amdgcn_s_setprio(0);
        }

        // ---- phase B: barrier (k16=2kt+1 landed; frees buf b0 for k16=2kt+3),
        //      stage k16=2kt+3, read kc1 frags, remaining 20 MFMAs
        if (kt < 7) pipe_barrier_vm4();
        else        pipe_barrier_vm0();     // tail: nothing newer in flight
        if (kt < 7) GLDS(2 * kt + 3, (2 * kt + 3) % 3);

        if (!skip) {
#pragma unroll
            for (int r2 = 0; r2 < 2; ++r2) {
                al[r2][1] = *(const half8*)(S + b1 * 8192 + ((arb + r2) * 2 + 1) * 512 + lane * 8);
                bh[r2][1] = *(const half8*)(S + b1 * 8192 + (8 + (brb + r2) * 2) * 512 + lane * 8);
            }
#pragma unroll
            for (int r2 = 0; r2 < 2; ++r2) {
                ah[r2][1] = *(const half8*)(S + b1 * 8192 + ((arb + r2) * 2) * 512 + lane * 8);
                bl[r2][1] = *(const half8*)(S + b1 * 8192 + (9 + (brb + r2) * 2) * 512 + lane * 8);
            }
            __builtin_amdgcn_s_setprio(1);
            // p1kc1, then p2kc0,p2kc1, p3kc0,p3kc1 -- order per acc element preserved
#pragma unroll
            for (int r2 = 0; r2 < 2; ++r2)
#pragma unroll
                for (int c = 0; c < 2; ++c)
                    acc[r2][c] = __builtin_amdgcn_mfma_f32_32x32x16_f16(al[r2][1], bh[c][1], acc[r2][c], 0, 0, 0);
#pragma unroll
            for (int kc = 0; kc < 2; ++kc)
#pragma unroll
                for (int r2 = 0; r2 < 2; ++r2)
#pragma unroll
                    for (int c = 0; c < 2; ++c)
                        acc[r2][c] = __builtin_amdgcn_mfma_f32_32x32x16_f16(ah[r2][kc], bl[c][kc], acc[r2][c], 0, 0, 0);
#pragma unroll
            for (int kc = 0; kc < 2; ++kc)
#pragma unroll
                for (int r2 = 0; r2 < 2; ++r2)
#pragma unroll
                    for (int c = 0; c < 2; ++c)
                        acc[r2][c] = __builtin_amdgcn_mfma_f32_32x32x16_f16(ah[r2][kc], bh[c][kc], acc[r2][c], 0, 0, 0);
            __builtin_amdgcn_s_setprio(0);
        }
    }
#undef GLDS

    if (skip) return;
    unsigned long long* bb = best + (size_t)n * LL;
    const float s = 1.f / 4194304.f;   // 2^-22
#pragma unroll
    for (int c = 0; c < 2; ++c) {
        int m = m0 + cw + c * 32 + r5;
        unsigned long long key = 0ull;
#pragma unroll
        for (int r2 = 0; r2 < 2; ++r2)
#pragma unroll
            for (int g = 0; g < 16; ++g) {
                int l = l0 + rw + r2 * 32 + (g & 3) + 8 * (g >> 2) + 4 * h5;
                if (l < m) {
                    float v = acc[r2][c][g] * s;
                    unsigned long long k2 =
                        ((unsigned long long)f2ord(v) << 32) |
                        (unsigned long long)(0xFFFFFFFFu - (unsigned)l);
                    key = (k2 > key) ? k2 : key;
                }
            }
        unsigned long long o = __shfl_xor(key, 32, 64);
        key = (o > key) ? o : key;
        if (h5 == 0 && key != 0ull) atomicMax(bb + m, key);
    }
}

// Kernel 3 (R0-proven form): unpack best, write S, U, ref_unfold, arg (float
// values), m==0 overrides. 4096 blocks (16 channel-groups of 4); XCD-pinned.
__global__ __launch_bounds__(256) void writeout(const float* __restrict__ yhat,
                                                const float* __restrict__ yprob,
                                                const unsigned long long* __restrict__ best,
                                                float* __restrict__ out) {
    int blk = blockIdx.x;                     // 0..4095
    int xcd = blk & 7;
    int n = xcd >> 1;
    int idx = (blk >> 3) + (xcd & 1) * 512;   // 0..1023
    int mb = idx >> 4;                        // 0..63
    int fc = idx & 15;                        // channel group of 4
    int tid = threadIdx.x;
    int mm = tid & 63;
    int fs = tid >> 6;                        // 0..3
    int c = fc * 4 + fs;
    int m = mb * 64 + mm;

    unsigned long long key = best[(size_t)n * LL + m];
    unsigned l = 0xFFFFFFFFu - (unsigned)(key & 0xFFFFFFFFull);
    float val = ord2f((unsigned)(key >> 32));
    bool zero = (m == 0);
    if (zero) l = 0;
    int ly = (int)(l >> 6), lx = (int)(l & 63);

    float* Sout = out;                       // [4,1,64,64]
    float* Uout = out + 16384;               // [4,1,64,64]
    float* Rout = out + 32768;               // [4,576,4096]
    float* Aout = out + 9469952;             // [4,4096] as float values

    if (fc == 0 && fs == 0) {
        float S = zero ? 1e-8f : fminf(fmaxf(val, 1e-8f), 1.0f);
        float U = zero ? 1e-8f : fminf(fmaxf(yprob[(size_t)n * LL + l], 1e-8f), 1.0f);
        Sout[(size_t)n * LL + m] = S;
        Uout[(size_t)n * LL + m] = U;
        Aout[(size_t)n * LL + m] = zero ? -1.0f : (float)l;
    }

    const float* src = yhat + (size_t)n * (Cc * LL);
    const float* plane = src + (size_t)c * LL;
    float* dst = Rout + (size_t)n * (576 * LL) + m;
    bool fast = (!zero) && (lx >= 1) && (lx <= 61);
#pragma unroll
    for (int r3 = 0; r3 < 3; ++r3) {
        int yy = ly + r3 - 1;
        bool rowok = (!zero) && (yy >= 0) && (yy < 64);
        float t0 = 0.f, t1 = 0.f, t2 = 0.f;
        if (rowok) {
            if (fast) {
                f4a v = *(const f4a*)(plane + yy * 64 + lx - 1);
                t0 = v.x; t1 = v.y; t2 = v.z;
            } else {
                if (lx > 0)  t0 = plane[yy * 64 + lx - 1];
                t1 = plane[yy * 64 + lx];
                if (lx < 63) t2 = plane[yy * 64 + lx + 1];
            }
        }
        size_t f = (size_t)(c * 9 + r3 * 3) * LL;
        __builtin_nontemporal_store(t0, dst + f);
        __builtin_nontemporal_store(t1, dst + f + LL);
        __builtin_nontemporal_store(t2, dst + f + 2 * (size_t)LL);
    }
}

extern "C" void kernel_launch(void* const* d_in, const int* in_sizes, int n_in,
                              void* d_out, int out_size, void* d_ws, size_t ws_size,
                              hipStream_t stream) {
    const float* yhat  = (const float*)d_in[0];
    const float* yprob = (const float*)d_in[1];
    float* out = (float*)d_out;

    unsigned short* VhT = (unsigned short*)d_ws;                       // 8 MiB (fragment-packed)
    unsigned short* VlT = (unsigned short*)((char*)d_ws + 8388608);    // 8 MiB (fragment-packed)
    unsigned long long* best =
        (unsigned long long*)((char*)d_ws + 16777216);                 // 128 KiB

    build_v<<<1024, 256, 0, stream>>>(yhat, VhT, VlT, best);
    simmax<<<Nn * TRI2, 256, 0, stream>>>(VhT, VlT, best);
    writeout<<<4096, 256, 0, stream>>>(yhat, yprob, best, out);
}